// Round 5
// baseline (377.760 us; speedup 1.0000x reference)
//
#include <hip/hip_runtime.h>

// MAF_Extractor R5 (= R4 + fix): plane-staged gather reads NCHW s_feat exactly
// once (coalesced), emits bf16 feat tiles in MFMA A-layout (B,27,16,256) in ws;
// MLP kernel holds feat fragments in registers across all 3 layers.
// R4 bug: projection staging covered only 256 of 432 points -> strided loop.

#define B_   64
#define N_   431
#define C_   256
#define H_   56
#define W_   56
#define HW_  3136
#define PPB  16
#define NT_  27
#define NPAD (NT_ * PPB)   // 432

#define Y0S  136           // 128+8 ushorts
#define Y1S  72            // 64+8

typedef __attribute__((ext_vector_type(8))) short short8;
typedef __attribute__((ext_vector_type(4))) float f32x4;

__device__ __forceinline__ ushort f2bf(float f) {
    unsigned u = __float_as_uint(f);
    u += 0x7fffu + ((u >> 16) & 1u);     // RNE
    return (ushort)(u >> 16);
}

#define WTOT (128 * 256 + 64 * 384 + 16 * 320)   // 62464 bf16 weight elems
#define GB_  (B_ * 64)                            // gather blocks: b x 4-ch groups

// ---------------- gather (+ weight convert) ----------------
__global__ __launch_bounds__(256, 2) void gather_kernel(
    const float* __restrict__ p,      // (B,N,3)
    const float* __restrict__ cam,    // (B,3)
    const float* __restrict__ sfeat,  // (B,C,H,W) fp32
    const float* __restrict__ W0,
    const float* __restrict__ W1,
    const float* __restrict__ W2,
    ushort* __restrict__ feat,        // (B,NT,16,C) bf16
    ushort* __restrict__ W0b,         // (128,256)
    ushort* __restrict__ W1b,         // (64,384)
    ushort* __restrict__ W2p)         // (16,320), rows 5..15 zero
{
    const int bx = blockIdx.x;
    if (bx >= GB_) {
        // ---- 8 trailing blocks: weight fp32 -> bf16 ----
        const int t0 = (bx - GB_) * 256 + threadIdx.x;   // 0..2047
        for (int i = t0; i < WTOT; i += 8 * 256) {
            if (i < 128 * 256) {
                W0b[i] = f2bf(W0[i]);
            } else if (i < 128 * 256 + 64 * 384) {
                const int j = i - 128 * 256;
                W1b[j] = f2bf(W1[j]);
            } else {
                const int j = i - (128 * 256 + 64 * 384);
                const int r = j / 320, c = j - r * 320;
                W2p[j] = (r < 5) ? f2bf(W2[r * 320 + c]) : (ushort)0;
            }
        }
        return;
    }

    __shared__ float planes[4][HW_];   // 50176 B
    __shared__ int   pidx[NPAD][4];    // 6912 B
    __shared__ float pw[NPAD][4];      // 6912 B  -> total 64000 B

    const int b  = bx >> 6;
    const int c0 = (bx & 63) * 4;
    const int t  = threadIdx.x;

    // stage 4 channel planes, coalesced float4
    #pragma unroll
    for (int j = 0; j < 4; ++j) {
        const float4* __restrict__ src =
            (const float4*)(sfeat + ((size_t)b * C_ + c0 + j) * HW_);
        for (int k = t; k < HW_ / 4; k += 256)
            *(float4*)&planes[j][k * 4] = src[k];
    }

    // stage per-point projection data — ALL NPAD points (R4 fix: strided loop)
    {
        const float s  = cam[b * 3 + 0];
        const float tx = cam[b * 3 + 1];
        const float ty = cam[b * 3 + 2];
        for (int n = t; n < NPAD; n += 256) {
            int   i00 = 0, i10 = 0, i01 = 0, i11 = 0;
            float w00 = 0.f, w10 = 0.f, w01 = 0.f, w11 = 0.f;
            if (n < N_) {
                const float px = p[((size_t)b * N_ + n) * 3 + 0];
                const float py = p[((size_t)b * N_ + n) * 3 + 1];
                const float x = (s * (px + tx) + 1.f) * 0.5f * (float)(W_ - 1);
                const float y = (s * (py + ty) + 1.f) * 0.5f * (float)(H_ - 1);
                const float x0f = floorf(x), y0f = floorf(y);
                const float wx1 = x - x0f, wx0 = 1.f - wx1;
                const float wy1 = y - y0f, wy0 = 1.f - wy1;
                const int ix0 = (int)x0f, iy0 = (int)y0f;
                const int ix1 = ix0 + 1,  iy1 = iy0 + 1;
                const bool vx0 = (ix0 >= 0) & (ix0 <= W_ - 1);
                const bool vx1 = (ix1 >= 0) & (ix1 <= W_ - 1);
                const bool vy0 = (iy0 >= 0) & (iy0 <= H_ - 1);
                const bool vy1 = (iy1 >= 0) & (iy1 <= H_ - 1);
                const int cx0 = min(max(ix0, 0), W_ - 1);
                const int cx1 = min(max(ix1, 0), W_ - 1);
                const int cy0 = min(max(iy0, 0), H_ - 1);
                const int cy1 = min(max(iy1, 0), H_ - 1);
                w00 = (vx0 & vy0) ? wx0 * wy0 : 0.f;
                w10 = (vx1 & vy0) ? wx1 * wy0 : 0.f;
                w01 = (vx0 & vy1) ? wx0 * wy1 : 0.f;
                w11 = (vx1 & vy1) ? wx1 * wy1 : 0.f;
                i00 = cy0 * W_ + cx0;  i10 = cy0 * W_ + cx1;
                i01 = cy1 * W_ + cx0;  i11 = cy1 * W_ + cx1;
            }
            pidx[n][0] = i00; pidx[n][1] = i10; pidx[n][2] = i01; pidx[n][3] = i11;
            pw[n][0] = w00;   pw[n][1] = w10;   pw[n][2] = w01;   pw[n][3] = w11;
        }
    }
    __syncthreads();

    // each thread: one point (all 4 channels), write ushort4 in A-tile layout
    for (int n = t; n < NPAD; n += 256) {
        const int   i00 = pidx[n][0], i10 = pidx[n][1], i01 = pidx[n][2], i11 = pidx[n][3];
        const float w00 = pw[n][0],   w10 = pw[n][1],   w01 = pw[n][2],   w11 = pw[n][3];
        ushort4 r;
        r.x = f2bf(w00 * planes[0][i00] + w10 * planes[0][i10] + w01 * planes[0][i01] + w11 * planes[0][i11]);
        r.y = f2bf(w00 * planes[1][i00] + w10 * planes[1][i10] + w01 * planes[1][i01] + w11 * planes[1][i11]);
        r.z = f2bf(w00 * planes[2][i00] + w10 * planes[2][i10] + w01 * planes[2][i01] + w11 * planes[2][i11]);
        r.w = f2bf(w00 * planes[3][i00] + w10 * planes[3][i10] + w01 * planes[3][i01] + w11 * planes[3][i11]);
        *(ushort4*)(feat + ((size_t)b * NPAD + n) * C_ + c0) = r;
    }
}

// ---------------- MLP (feat fragments in registers) ----------------
__global__ __launch_bounds__(256, 4) void mlp_kernel(
    const ushort* __restrict__ feat,  // (B,NT,16,256) bf16
    const ushort* __restrict__ W0b,
    const float* __restrict__ b0,
    const ushort* __restrict__ W1b,
    const float* __restrict__ b1,
    const ushort* __restrict__ W2p,
    const float* __restrict__ b2,
    float* __restrict__ out)          // (B,5,N)
{
    __shared__ ushort y0_s[PPB * Y0S];
    __shared__ ushort y1_s[PPB * Y1S];

    const int tid  = threadIdx.x;
    const int w    = tid >> 6;
    const int l    = tid & 63;
    const int m    = l & 15;
    const int q    = l >> 4;
    const int tile = blockIdx.x;
    const int b    = blockIdx.y;
    const int n0   = tile * PPB;

    // load 8 feat A-fragments once; reused by all 3 layers (concat maps back)
    const ushort* __restrict__ fb =
        feat + (((size_t)b * NT_ + tile) * PPB + m) * C_ + 8 * q;
    short8 af[8];
    #pragma unroll
    for (int ks = 0; ks < 8; ++ks) af[ks] = *(const short8*)(fb + 32 * ks);

    // ---- layer0 (128 <- 256): wave w -> output tiles 2w, 2w+1
    {
        f32x4 acc0 = {0.f, 0.f, 0.f, 0.f};
        f32x4 acc1 = {0.f, 0.f, 0.f, 0.f};
        const ushort* __restrict__ wr0 = W0b + ((size_t)(2 * w) * 16 + m) * 256 + 8 * q;
        const ushort* __restrict__ wr1 = wr0 + 16 * 256;
        #pragma unroll
        for (int ks = 0; ks < 8; ++ks) {
            const short8 w0 = *(const short8*)(wr0 + 32 * ks);
            const short8 w1 = *(const short8*)(wr1 + 32 * ks);
            acc0 = __builtin_amdgcn_mfma_f32_16x16x32_bf16(af[ks], w0, acc0, 0, 0, 0);
            acc1 = __builtin_amdgcn_mfma_f32_16x16x32_bf16(af[ks], w1, acc1, 0, 0, 0);
        }
        const int o0 = (2 * w) * 16 + m, o1 = o0 + 16;
        const float bias0 = b0[o0], bias1 = b0[o1];
        #pragma unroll
        for (int r = 0; r < 4; ++r) {
            float v0 = acc0[r] + bias0; v0 = (v0 > 0.f) ? v0 : 0.01f * v0;
            float v1 = acc1[r] + bias1; v1 = (v1 > 0.f) ? v1 : 0.01f * v1;
            y0_s[(q * 4 + r) * Y0S + o0] = f2bf(v0);
            y0_s[(q * 4 + r) * Y0S + o1] = f2bf(v1);
        }
    }
    __syncthreads();

    // ---- layer1 (64 <- [128 y0 | 256 feat]): wave w -> output tile w
    {
        f32x4 acc = {0.f, 0.f, 0.f, 0.f};
        const ushort* __restrict__ wr = W1b + ((size_t)w * 16 + m) * 384 + 8 * q;
        #pragma unroll
        for (int ks = 0; ks < 4; ++ks) {
            const short8 a  = *(const short8*)(y0_s + m * Y0S + 32 * ks + 8 * q);
            const short8 bb = *(const short8*)(wr + 32 * ks);
            acc = __builtin_amdgcn_mfma_f32_16x16x32_bf16(a, bb, acc, 0, 0, 0);
        }
        #pragma unroll
        for (int ks = 4; ks < 12; ++ks) {
            const short8 bb = *(const short8*)(wr + 32 * ks);
            acc = __builtin_amdgcn_mfma_f32_16x16x32_bf16(af[ks - 4], bb, acc, 0, 0, 0);
        }
        const int o = w * 16 + m;
        const float bias = b1[o];
        #pragma unroll
        for (int r = 0; r < 4; ++r) {
            float v = acc[r] + bias; v = (v > 0.f) ? v : 0.01f * v;
            y1_s[(q * 4 + r) * Y1S + o] = f2bf(v);
        }
    }
    __syncthreads();

    // ---- layer2 (5 <- [64 y1 | 256 feat]) on wave 0, relu, store
    if (w == 0) {
        f32x4 acc = {0.f, 0.f, 0.f, 0.f};
        const ushort* __restrict__ wr = W2p + (size_t)m * 320 + 8 * q;
        #pragma unroll
        for (int ks = 0; ks < 2; ++ks) {
            const short8 a  = *(const short8*)(y1_s + m * Y1S + 32 * ks + 8 * q);
            const short8 bb = *(const short8*)(wr + 32 * ks);
            acc = __builtin_amdgcn_mfma_f32_16x16x32_bf16(a, bb, acc, 0, 0, 0);
        }
        #pragma unroll
        for (int ks = 2; ks < 10; ++ks) {
            const short8 bb = *(const short8*)(wr + 32 * ks);
            acc = __builtin_amdgcn_mfma_f32_16x16x32_bf16(af[ks - 2], bb, acc, 0, 0, 0);
        }
        if (m < 5) {
            const float bias = b2[m];
            #pragma unroll
            for (int r = 0; r < 4; ++r) {
                const int n = n0 + q * 4 + r;
                if (n < N_) {
                    float v = acc[r] + bias;
                    out[((size_t)b * 5 + m) * N_ + n] = (v > 0.f) ? v : 0.f;
                }
            }
        }
    }
}

// ---------------- fp32 NCHW fallback (ws too small) ----------------
__global__ __launch_bounds__(256, 4) void maf_fallback_kernel(
    const float* __restrict__ p, const float* __restrict__ cam,
    const float* __restrict__ sfeat,
    const float* __restrict__ W0, const float* __restrict__ b0,
    const float* __restrict__ W1, const float* __restrict__ b1,
    const float* __restrict__ W2, const float* __restrict__ b2,
    float* __restrict__ out)
{
    __shared__ float feat_s[PPB][C_ + 4];
    __shared__ float y0_s[PPB][128 + 4];
    __shared__ float y1_s[PPB][64 + 4];

    const int tid = threadIdx.x;
    const int b   = blockIdx.y;
    const int n0  = blockIdx.x * PPB;
    const float s  = cam[b * 3 + 0];
    const float tx = cam[b * 3 + 1];
    const float ty = cam[b * 3 + 2];
    {
        const int c = tid;
        const float* __restrict__ fb = sfeat + ((size_t)b * C_ + c) * HW_;
        for (int pp = 0; pp < PPB; ++pp) {
            const int n = n0 + pp;
            float val = 0.f;
            if (n < N_) {
                const float px = p[((size_t)b * N_ + n) * 3 + 0];
                const float py = p[((size_t)b * N_ + n) * 3 + 1];
                const float x = (s * (px + tx) + 1.f) * 0.5f * (float)(W_ - 1);
                const float y = (s * (py + ty) + 1.f) * 0.5f * (float)(H_ - 1);
                const float x0f = floorf(x), y0f = floorf(y);
                const float wx1 = x - x0f, wx0 = 1.f - wx1;
                const float wy1 = y - y0f, wy0 = 1.f - wy1;
                const int ix0 = (int)x0f, iy0 = (int)y0f;
                const int ix1 = ix0 + 1,  iy1 = iy0 + 1;
                const bool vx0 = (ix0 >= 0) & (ix0 <= W_ - 1);
                const bool vx1 = (ix1 >= 0) & (ix1 <= W_ - 1);
                const bool vy0 = (iy0 >= 0) & (iy0 <= H_ - 1);
                const bool vy1 = (iy1 >= 0) & (iy1 <= H_ - 1);
                const int cx0 = min(max(ix0, 0), W_ - 1);
                const int cx1 = min(max(ix1, 0), W_ - 1);
                const int cy0 = min(max(iy0, 0), H_ - 1);
                const int cy1 = min(max(iy1, 0), H_ - 1);
                const float w00 = (vx0 & vy0) ? wx0 * wy0 : 0.f;
                const float w10 = (vx1 & vy0) ? wx1 * wy0 : 0.f;
                const float w01 = (vx0 & vy1) ? wx0 * wy1 : 0.f;
                const float w11 = (vx1 & vy1) ? wx1 * wy1 : 0.f;
                val = w00 * fb[cy0 * W_ + cx0] + w10 * fb[cy0 * W_ + cx1]
                    + w01 * fb[cy1 * W_ + cx0] + w11 * fb[cy1 * W_ + cx1];
            }
            feat_s[pp][c] = val;
        }
    }
    __syncthreads();
    {
        const int o = tid & 127, pg = tid >> 7, p0 = pg * 8;
        const float* __restrict__ wr = W0 + (size_t)o * 256;
        float acc[8] = {0, 0, 0, 0, 0, 0, 0, 0};
        for (int k = 0; k < 256; k += 4) {
            const float4 w = *(const float4*)(wr + k);
            for (int i = 0; i < 8; ++i) {
                const float4 f = *(const float4*)&feat_s[p0 + i][k];
                acc[i] += w.x * f.x + w.y * f.y + w.z * f.z + w.w * f.w;
            }
        }
        const float bias = b0[o];
        for (int i = 0; i < 8; ++i) {
            const float v = acc[i] + bias;
            y0_s[p0 + i][o] = (v > 0.f) ? v : 0.01f * v;
        }
    }
    __syncthreads();
    {
        const int o = tid & 63, pg = tid >> 6, p0 = pg * 4;
        const float* __restrict__ wr = W1 + (size_t)o * 384;
        float acc[4] = {0, 0, 0, 0};
        for (int k = 0; k < 128; k += 4) {
            const float4 w = *(const float4*)(wr + k);
            for (int i = 0; i < 4; ++i) {
                const float4 f = *(const float4*)&y0_s[p0 + i][k];
                acc[i] += w.x * f.x + w.y * f.y + w.z * f.z + w.w * f.w;
            }
        }
        for (int k = 0; k < 256; k += 4) {
            const float4 w = *(const float4*)(wr + 128 + k);
            for (int i = 0; i < 4; ++i) {
                const float4 f = *(const float4*)&feat_s[p0 + i][k];
                acc[i] += w.x * f.x + w.y * f.y + w.z * f.z + w.w * f.w;
            }
        }
        const float bias = b1[o];
        for (int i = 0; i < 4; ++i) {
            const float v = acc[i] + bias;
            y1_s[p0 + i][o] = (v > 0.f) ? v : 0.01f * v;
        }
    }
    __syncthreads();
    if (tid < 80) {
        const int o = tid >> 4, pp = tid & 15;
        const float* __restrict__ wr = W2 + (size_t)o * 320;
        float acc = 0.f;
        for (int k = 0; k < 64; k += 4) {
            const float4 w = *(const float4*)(wr + k);
            const float4 f = *(const float4*)&y1_s[pp][k];
            acc += w.x * f.x + w.y * f.y + w.z * f.z + w.w * f.w;
        }
        for (int k = 0; k < 256; k += 4) {
            const float4 w = *(const float4*)(wr + 64 + k);
            const float4 f = *(const float4*)&feat_s[pp][k];
            acc += w.x * f.x + w.y * f.y + w.z * f.z + w.w * f.w;
        }
        const int n = n0 + pp;
        if (n < N_) {
            float v = acc + b2[o];
            out[((size_t)b * 5 + o) * N_ + n] = (v > 0.f) ? v : 0.f;
        }
    }
}

extern "C" void kernel_launch(void* const* d_in, const int* in_sizes, int n_in,
                              void* d_out, int out_size, void* d_ws, size_t ws_size,
                              hipStream_t stream) {
    const float* p     = (const float*)d_in[0];
    const float* cam   = (const float*)d_in[1];
    const float* sfeat = (const float*)d_in[2];
    const float* W0    = (const float*)d_in[3];
    const float* b0    = (const float*)d_in[4];
    const float* W1    = (const float*)d_in[5];
    const float* b1    = (const float*)d_in[6];
    const float* W2    = (const float*)d_in[7];
    const float* b2    = (const float*)d_in[8];
    float* out = (float*)d_out;

    const size_t feat_elems = (size_t)B_ * NPAD * C_;   // 7,077,888 bf16
    size_t off = feat_elems;
    const size_t w0_off = off; off += 128 * 256;
    const size_t w1_off = off; off += 64 * 384;
    const size_t w2_off = off; off += 16 * 320;
    const size_t need = off * sizeof(ushort);           // ~14.3 MB

    if (ws_size >= need) {
        ushort* feat = (ushort*)d_ws;
        ushort* W0b  = feat + w0_off;
        ushort* W1b  = feat + w1_off;
        ushort* W2p  = feat + w2_off;
        gather_kernel<<<GB_ + 8, 256, 0, stream>>>(
            p, cam, sfeat, W0, W1, W2, feat, W0b, W1b, W2p);
        mlp_kernel<<<dim3(NT_, B_), 256, 0, stream>>>(
            feat, W0b, b0, W1b, b1, W2p, b2, out);
    } else {
        maf_fallback_kernel<<<dim3(NT_, B_), 256, 0, stream>>>(
            p, cam, sfeat, W0, b0, W1, b1, W2, b2, out);
    }
}

// Round 6
// 336.280 us; speedup vs baseline: 1.1234x; 1.1234x over previous
//
#include <hip/hip_runtime.h>

// MAF_Extractor R6: single-pass plane-staged gather with bf16-packed planes
// (25 KB LDS -> 6 blocks/CU) and contiguous per-block feat writes
// (B,64,NPAD,4) layout; MLP rebuilds MFMA A-fragments from two uint2 loads.
// B=64 N=431 C=256 H=W=56.

#define B_   64
#define N_   431
#define C_   256
#define H_   56
#define W_   56
#define HW_  3136
#define PPB  16
#define NT_  27
#define NPAD (NT_ * PPB)   // 432

#define Y0S  136           // 128+8 ushorts
#define Y1S  72            // 64+8

typedef __attribute__((ext_vector_type(8))) short short8;
typedef __attribute__((ext_vector_type(4))) float f32x4;

__device__ __forceinline__ ushort f2bf(float f) {
    unsigned u = __float_as_uint(f);
    u += 0x7fffu + ((u >> 16) & 1u);     // RNE
    return (ushort)(u >> 16);
}
__device__ __forceinline__ uint pack2(float lo, float hi) {
    return (uint)f2bf(lo) | ((uint)f2bf(hi) << 16);
}
__device__ __forceinline__ float lo16(uint u) { return __uint_as_float(u << 16); }
__device__ __forceinline__ float hi16(uint u) { return __uint_as_float(u & 0xffff0000u); }

#define WTOT (128 * 256 + 64 * 384 + 16 * 320)   // 62464 bf16 weight elems
#define GB_  (B_ * 64)                            // gather blocks: b x 4-ch groups

// ---------------- gather (+ weight convert) ----------------
__global__ __launch_bounds__(256, 6) void gather_kernel(
    const float* __restrict__ p,      // (B,N,3)
    const float* __restrict__ cam,    // (B,3)
    const float* __restrict__ sfeat,  // (B,C,H,W) fp32
    const float* __restrict__ W0,
    const float* __restrict__ W1,
    const float* __restrict__ W2,
    ushort* __restrict__ feat,        // (B,64,NPAD,4) bf16
    ushort* __restrict__ W0b,         // (128,256)
    ushort* __restrict__ W1b,         // (64,384)
    ushort* __restrict__ W2p)         // (16,320), rows 5..15 zero
{
    const int bx = blockIdx.x;
    if (bx >= GB_) {
        // ---- 8 trailing blocks: weight fp32 -> bf16 ----
        const int t0 = (bx - GB_) * 256 + threadIdx.x;   // 0..2047
        for (int i = t0; i < WTOT; i += 8 * 256) {
            if (i < 128 * 256) {
                W0b[i] = f2bf(W0[i]);
            } else if (i < 128 * 256 + 64 * 384) {
                const int j = i - 128 * 256;
                W1b[j] = f2bf(W1[j]);
            } else {
                const int j = i - (128 * 256 + 64 * 384);
                const int r = j / 320, c = j - r * 320;
                W2p[j] = (r < 5) ? f2bf(W2[r * 320 + c]) : (ushort)0;
            }
        }
        return;
    }

    __shared__ uint plane01[HW_];     // ch c0,c0+1 packed bf16   12544 B
    __shared__ uint plane23[HW_];     // ch c0+2,c0+3             12544 B

    const int b  = bx >> 6;
    const int cg = bx & 63;
    const int c0 = cg * 4;
    const int t  = threadIdx.x;

    // stage 4 channel planes, coalesced float4, packed to bf16 pairs
    {
        const float4* __restrict__ s0 = (const float4*)(sfeat + ((size_t)b * C_ + c0 + 0) * HW_);
        const float4* __restrict__ s1 = (const float4*)(sfeat + ((size_t)b * C_ + c0 + 1) * HW_);
        const float4* __restrict__ s2 = (const float4*)(sfeat + ((size_t)b * C_ + c0 + 2) * HW_);
        const float4* __restrict__ s3 = (const float4*)(sfeat + ((size_t)b * C_ + c0 + 3) * HW_);
        for (int k = t; k < HW_ / 4; k += 256) {
            const float4 a = s0[k], bb = s1[k];
            uint4 u01;
            u01.x = pack2(a.x, bb.x); u01.y = pack2(a.y, bb.y);
            u01.z = pack2(a.z, bb.z); u01.w = pack2(a.w, bb.w);
            *(uint4*)&plane01[k * 4] = u01;
            const float4 c = s2[k], d = s3[k];
            uint4 u23;
            u23.x = pack2(c.x, d.x); u23.y = pack2(c.y, d.y);
            u23.z = pack2(c.z, d.z); u23.w = pack2(c.w, d.w);
            *(uint4*)&plane23[k * 4] = u23;
        }
    }
    __syncthreads();

    // gather: each thread handles points t, t+256 (projection inline)
    const float s  = cam[b * 3 + 0];
    const float tx = cam[b * 3 + 1];
    const float ty = cam[b * 3 + 2];
    ushort* __restrict__ fdst = feat + ((size_t)b * 64 + cg) * NPAD * 4;

    for (int n = t; n < NPAD; n += 256) {
        int   i00 = 0, i10 = 0, i01 = 0, i11 = 0;
        float w00 = 0.f, w10 = 0.f, w01 = 0.f, w11 = 0.f;
        if (n < N_) {
            const float px = p[((size_t)b * N_ + n) * 3 + 0];
            const float py = p[((size_t)b * N_ + n) * 3 + 1];
            const float x = (s * (px + tx) + 1.f) * 0.5f * (float)(W_ - 1);
            const float y = (s * (py + ty) + 1.f) * 0.5f * (float)(H_ - 1);
            const float x0f = floorf(x), y0f = floorf(y);
            const float wx1 = x - x0f, wx0 = 1.f - wx1;
            const float wy1 = y - y0f, wy0 = 1.f - wy1;
            const int ix0 = (int)x0f, iy0 = (int)y0f;
            const int ix1 = ix0 + 1,  iy1 = iy0 + 1;
            const bool vx0 = (ix0 >= 0) & (ix0 <= W_ - 1);
            const bool vx1 = (ix1 >= 0) & (ix1 <= W_ - 1);
            const bool vy0 = (iy0 >= 0) & (iy0 <= H_ - 1);
            const bool vy1 = (iy1 >= 0) & (iy1 <= H_ - 1);
            const int cx0 = min(max(ix0, 0), W_ - 1);
            const int cx1 = min(max(ix1, 0), W_ - 1);
            const int cy0 = min(max(iy0, 0), H_ - 1);
            const int cy1 = min(max(iy1, 0), H_ - 1);
            w00 = (vx0 & vy0) ? wx0 * wy0 : 0.f;
            w10 = (vx1 & vy0) ? wx1 * wy0 : 0.f;
            w01 = (vx0 & vy1) ? wx0 * wy1 : 0.f;
            w11 = (vx1 & vy1) ? wx1 * wy1 : 0.f;
            i00 = cy0 * W_ + cx0;  i10 = cy0 * W_ + cx1;
            i01 = cy1 * W_ + cx0;  i11 = cy1 * W_ + cx1;
        }
        const uint a00 = plane01[i00], a10 = plane01[i10], a01 = plane01[i01], a11 = plane01[i11];
        const uint c00 = plane23[i00], c10 = plane23[i10], c01 = plane23[i01], c11 = plane23[i11];
        const float v0 = w00 * lo16(a00) + w10 * lo16(a10) + w01 * lo16(a01) + w11 * lo16(a11);
        const float v1 = w00 * hi16(a00) + w10 * hi16(a10) + w01 * hi16(a01) + w11 * hi16(a11);
        const float v2 = w00 * lo16(c00) + w10 * lo16(c10) + w01 * lo16(c01) + w11 * lo16(c11);
        const float v3 = w00 * hi16(c00) + w10 * hi16(c10) + w01 * hi16(c01) + w11 * hi16(c11);
        ushort4 r;
        r.x = f2bf(v0); r.y = f2bf(v1); r.z = f2bf(v2); r.w = f2bf(v3);
        *(ushort4*)(fdst + (size_t)n * 4) = r;   // contiguous per-block region
    }
}

// ---------------- MLP (feat fragments in registers) ----------------
__global__ __launch_bounds__(256, 4) void mlp_kernel(
    const ushort* __restrict__ feat,  // (B,64,NPAD,4) bf16
    const ushort* __restrict__ W0b,
    const float* __restrict__ b0,
    const ushort* __restrict__ W1b,
    const float* __restrict__ b1,
    const ushort* __restrict__ W2p,
    const float* __restrict__ b2,
    float* __restrict__ out)          // (B,5,N)
{
    __shared__ ushort y0_s[PPB * Y0S];
    __shared__ ushort y1_s[PPB * Y1S];

    const int tid  = threadIdx.x;
    const int w    = tid >> 6;
    const int l    = tid & 63;
    const int m    = l & 15;
    const int q    = l >> 4;
    const int tile = blockIdx.x;
    const int b    = blockIdx.y;
    const int n0   = tile * PPB;
    const int n    = n0 + m;          // this lane's point row

    // load 8 feat A-fragments once; af[ks] = channels 32ks+8q .. +7, point n.
    // (B,64,NPAD,4) layout: cg0 = 8ks+2q gives ch 4*cg0..+3, cg0+1 the next 4.
    const ushort* __restrict__ fb = feat + (size_t)b * 64 * NPAD * 4;
    short8 af[8];
    #pragma unroll
    for (int ks = 0; ks < 8; ++ks) {
        const int cg0 = 8 * ks + 2 * q;
        union { short8 v; uint2 u[2]; } tmp;
        tmp.u[0] = *(const uint2*)(fb + ((size_t)cg0 * NPAD + n) * 4);
        tmp.u[1] = *(const uint2*)(fb + ((size_t)(cg0 + 1) * NPAD + n) * 4);
        af[ks] = tmp.v;
    }

    // ---- layer0 (128 <- 256): wave w -> output tiles 2w, 2w+1
    {
        f32x4 acc0 = {0.f, 0.f, 0.f, 0.f};
        f32x4 acc1 = {0.f, 0.f, 0.f, 0.f};
        const ushort* __restrict__ wr0 = W0b + ((size_t)(2 * w) * 16 + m) * 256 + 8 * q;
        const ushort* __restrict__ wr1 = wr0 + 16 * 256;
        #pragma unroll
        for (int ks = 0; ks < 8; ++ks) {
            const short8 w0 = *(const short8*)(wr0 + 32 * ks);
            const short8 w1 = *(const short8*)(wr1 + 32 * ks);
            acc0 = __builtin_amdgcn_mfma_f32_16x16x32_bf16(af[ks], w0, acc0, 0, 0, 0);
            acc1 = __builtin_amdgcn_mfma_f32_16x16x32_bf16(af[ks], w1, acc1, 0, 0, 0);
        }
        const int o0 = (2 * w) * 16 + m, o1 = o0 + 16;
        const float bias0 = b0[o0], bias1 = b0[o1];
        #pragma unroll
        for (int r = 0; r < 4; ++r) {
            float v0 = acc0[r] + bias0; v0 = (v0 > 0.f) ? v0 : 0.01f * v0;
            float v1 = acc1[r] + bias1; v1 = (v1 > 0.f) ? v1 : 0.01f * v1;
            y0_s[(q * 4 + r) * Y0S + o0] = f2bf(v0);
            y0_s[(q * 4 + r) * Y0S + o1] = f2bf(v1);
        }
    }
    __syncthreads();

    // ---- layer1 (64 <- [128 y0 | 256 feat]): wave w -> output tile w
    {
        f32x4 acc = {0.f, 0.f, 0.f, 0.f};
        const ushort* __restrict__ wr = W1b + ((size_t)w * 16 + m) * 384 + 8 * q;
        #pragma unroll
        for (int ks = 0; ks < 4; ++ks) {
            const short8 a  = *(const short8*)(y0_s + m * Y0S + 32 * ks + 8 * q);
            const short8 bb = *(const short8*)(wr + 32 * ks);
            acc = __builtin_amdgcn_mfma_f32_16x16x32_bf16(a, bb, acc, 0, 0, 0);
        }
        #pragma unroll
        for (int ks = 4; ks < 12; ++ks) {
            const short8 bb = *(const short8*)(wr + 32 * ks);
            acc = __builtin_amdgcn_mfma_f32_16x16x32_bf16(af[ks - 4], bb, acc, 0, 0, 0);
        }
        const int o = w * 16 + m;
        const float bias = b1[o];
        #pragma unroll
        for (int r = 0; r < 4; ++r) {
            float v = acc[r] + bias; v = (v > 0.f) ? v : 0.01f * v;
            y1_s[(q * 4 + r) * Y1S + o] = f2bf(v);
        }
    }
    __syncthreads();

    // ---- layer2 (5 <- [64 y1 | 256 feat]) on wave 0, relu, store
    if (w == 0) {
        f32x4 acc = {0.f, 0.f, 0.f, 0.f};
        const ushort* __restrict__ wr = W2p + (size_t)m * 320 + 8 * q;
        #pragma unroll
        for (int ks = 0; ks < 2; ++ks) {
            const short8 a  = *(const short8*)(y1_s + m * Y1S + 32 * ks + 8 * q);
            const short8 bb = *(const short8*)(wr + 32 * ks);
            acc = __builtin_amdgcn_mfma_f32_16x16x32_bf16(a, bb, acc, 0, 0, 0);
        }
        #pragma unroll
        for (int ks = 2; ks < 10; ++ks) {
            const short8 bb = *(const short8*)(wr + 32 * ks);
            acc = __builtin_amdgcn_mfma_f32_16x16x32_bf16(af[ks - 2], bb, acc, 0, 0, 0);
        }
        if (m < 5) {
            const float bias = b2[m];
            #pragma unroll
            for (int r = 0; r < 4; ++r) {
                const int nn = n0 + q * 4 + r;
                if (nn < N_) {
                    float v = acc[r] + bias;
                    out[((size_t)b * 5 + m) * N_ + nn] = (v > 0.f) ? v : 0.f;
                }
            }
        }
    }
}

// ---------------- fp32 NCHW fallback (ws too small) ----------------
__global__ __launch_bounds__(256, 4) void maf_fallback_kernel(
    const float* __restrict__ p, const float* __restrict__ cam,
    const float* __restrict__ sfeat,
    const float* __restrict__ W0, const float* __restrict__ b0,
    const float* __restrict__ W1, const float* __restrict__ b1,
    const float* __restrict__ W2, const float* __restrict__ b2,
    float* __restrict__ out)
{
    __shared__ float feat_s[PPB][C_ + 4];
    __shared__ float y0_s[PPB][128 + 4];
    __shared__ float y1_s[PPB][64 + 4];

    const int tid = threadIdx.x;
    const int b   = blockIdx.y;
    const int n0  = blockIdx.x * PPB;
    const float s  = cam[b * 3 + 0];
    const float tx = cam[b * 3 + 1];
    const float ty = cam[b * 3 + 2];
    {
        const int c = tid;
        const float* __restrict__ fb = sfeat + ((size_t)b * C_ + c) * HW_;
        for (int pp = 0; pp < PPB; ++pp) {
            const int n = n0 + pp;
            float val = 0.f;
            if (n < N_) {
                const float px = p[((size_t)b * N_ + n) * 3 + 0];
                const float py = p[((size_t)b * N_ + n) * 3 + 1];
                const float x = (s * (px + tx) + 1.f) * 0.5f * (float)(W_ - 1);
                const float y = (s * (py + ty) + 1.f) * 0.5f * (float)(H_ - 1);
                const float x0f = floorf(x), y0f = floorf(y);
                const float wx1 = x - x0f, wx0 = 1.f - wx1;
                const float wy1 = y - y0f, wy0 = 1.f - wy1;
                const int ix0 = (int)x0f, iy0 = (int)y0f;
                const int ix1 = ix0 + 1,  iy1 = iy0 + 1;
                const bool vx0 = (ix0 >= 0) & (ix0 <= W_ - 1);
                const bool vx1 = (ix1 >= 0) & (ix1 <= W_ - 1);
                const bool vy0 = (iy0 >= 0) & (iy0 <= H_ - 1);
                const bool vy1 = (iy1 >= 0) & (iy1 <= H_ - 1);
                const int cx0 = min(max(ix0, 0), W_ - 1);
                const int cx1 = min(max(ix1, 0), W_ - 1);
                const int cy0 = min(max(iy0, 0), H_ - 1);
                const int cy1 = min(max(iy1, 0), H_ - 1);
                const float w00 = (vx0 & vy0) ? wx0 * wy0 : 0.f;
                const float w10 = (vx1 & vy0) ? wx1 * wy0 : 0.f;
                const float w01 = (vx0 & vy1) ? wx0 * wy1 : 0.f;
                const float w11 = (vx1 & vy1) ? wx1 * wy1 : 0.f;
                val = w00 * fb[cy0 * W_ + cx0] + w10 * fb[cy0 * W_ + cx1]
                    + w01 * fb[cy1 * W_ + cx0] + w11 * fb[cy1 * W_ + cx1];
            }
            feat_s[pp][c] = val;
        }
    }
    __syncthreads();
    {
        const int o = tid & 127, pg = tid >> 7, p0 = pg * 8;
        const float* __restrict__ wr = W0 + (size_t)o * 256;
        float acc[8] = {0, 0, 0, 0, 0, 0, 0, 0};
        for (int k = 0; k < 256; k += 4) {
            const float4 w = *(const float4*)(wr + k);
            for (int i = 0; i < 8; ++i) {
                const float4 f = *(const float4*)&feat_s[p0 + i][k];
                acc[i] += w.x * f.x + w.y * f.y + w.z * f.z + w.w * f.w;
            }
        }
        const float bias = b0[o];
        for (int i = 0; i < 8; ++i) {
            const float v = acc[i] + bias;
            y0_s[p0 + i][o] = (v > 0.f) ? v : 0.01f * v;
        }
    }
    __syncthreads();
    {
        const int o = tid & 63, pg = tid >> 6, p0 = pg * 4;
        const float* __restrict__ wr = W1 + (size_t)o * 384;
        float acc[4] = {0, 0, 0, 0};
        for (int k = 0; k < 128; k += 4) {
            const float4 w = *(const float4*)(wr + k);
            for (int i = 0; i < 4; ++i) {
                const float4 f = *(const float4*)&y0_s[p0 + i][k];
                acc[i] += w.x * f.x + w.y * f.y + w.z * f.z + w.w * f.w;
            }
        }
        for (int k = 0; k < 256; k += 4) {
            const float4 w = *(const float4*)(wr + 128 + k);
            for (int i = 0; i < 4; ++i) {
                const float4 f = *(const float4*)&feat_s[p0 + i][k];
                acc[i] += w.x * f.x + w.y * f.y + w.z * f.z + w.w * f.w;
            }
        }
        const float bias = b1[o];
        for (int i = 0; i < 4; ++i) {
            const float v = acc[i] + bias;
            y1_s[p0 + i][o] = (v > 0.f) ? v : 0.01f * v;
        }
    }
    __syncthreads();
    if (tid < 80) {
        const int o = tid >> 4, pp = tid & 15;
        const float* __restrict__ wr = W2 + (size_t)o * 320;
        float acc = 0.f;
        for (int k = 0; k < 64; k += 4) {
            const float4 w = *(const float4*)(wr + k);
            const float4 f = *(const float4*)&y1_s[pp][k];
            acc += w.x * f.x + w.y * f.y + w.z * f.z + w.w * f.w;
        }
        for (int k = 0; k < 256; k += 4) {
            const float4 w = *(const float4*)(wr + 64 + k);
            const float4 f = *(const float4*)&feat_s[pp][k];
            acc += w.x * f.x + w.y * f.y + w.z * f.z + w.w * f.w;
        }
        const int n = n0 + pp;
        if (n < N_) {
            float v = acc + b2[o];
            out[((size_t)b * 5 + o) * N_ + n] = (v > 0.f) ? v : 0.f;
        }
    }
}

extern "C" void kernel_launch(void* const* d_in, const int* in_sizes, int n_in,
                              void* d_out, int out_size, void* d_ws, size_t ws_size,
                              hipStream_t stream) {
    const float* p     = (const float*)d_in[0];
    const float* cam   = (const float*)d_in[1];
    const float* sfeat = (const float*)d_in[2];
    const float* W0    = (const float*)d_in[3];
    const float* b0    = (const float*)d_in[4];
    const float* W1    = (const float*)d_in[5];
    const float* b1    = (const float*)d_in[6];
    const float* W2    = (const float*)d_in[7];
    const float* b2    = (const float*)d_in[8];
    float* out = (float*)d_out;

    const size_t feat_elems = (size_t)B_ * 64 * NPAD * 4;   // 7,077,888 bf16
    size_t off = feat_elems;
    const size_t w0_off = off; off += 128 * 256;
    const size_t w1_off = off; off += 64 * 384;
    const size_t w2_off = off; off += 16 * 320;
    const size_t need = off * sizeof(ushort);               // ~14.3 MB

    if (ws_size >= need) {
        ushort* feat = (ushort*)d_ws;
        ushort* W0b  = feat + w0_off;
        ushort* W1b  = feat + w1_off;
        ushort* W2p  = feat + w2_off;
        gather_kernel<<<GB_ + 8, 256, 0, stream>>>(
            p, cam, sfeat, W0, W1, W2, feat, W0b, W1b, W2p);
        mlp_kernel<<<dim3(NT_, B_), 256, 0, stream>>>(
            feat, W0b, b0, W1b, b1, W2p, b2, out);
    } else {
        maf_fallback_kernel<<<dim3(NT_, B_), 256, 0, stream>>>(
            p, cam, sfeat, W0, b0, W1, b1, W2, b2, out);
    }
}